// Round 6
// baseline (169.397 us; speedup 1.0000x reference)
//
#include <hip/hip_runtime.h>

typedef float v2f __attribute__((ext_vector_type(2)));
typedef float v4f __attribute__((ext_vector_type(4)));

#define IMG_H 1080
#define IMG_W 1920
#define NBATCH 8
#define LSTRIP 9             // output rows per lane
#define BROWS (4*LSTRIP)     // 36 rows per block (4 wave-uniform strips)
#define NK (LSTRIP+4)        // 13 schedule iterations

// R6 = R5 (packed-fp32 fused Shi-Tomasi) with ONE change: all stores moved
// out of the ring loop into a terminal burst. Theory: vmcnt is a single
// in-order counter for loads AND stores; R2-R5's in-loop (nontemporal)
// stores sat between prefetch loads, so every row-consume s_waitcnt also
// waited a store ack from HBM -> ~3000-cycle iterations, both pipes idle.
// Batching outputs in registers (9 x float4) removes stores from the load
// critical path entirely.

static __device__ __forceinline__ v2f vfma2(v2f a, v2f b, v2f c) {
    return __builtin_elementwise_fma(a, b, c);
}

template<bool EDGE>
__device__ __forceinline__ void st_body(const float* __restrict__ g,
                                        float* __restrict__ outb,
                                        int vb, int s0) {
    const bool eL = EDGE && (vb == 0);
    const bool eR = EDGE && (vb == IMG_W - 4);
    int wb = vb - 4;
    if (EDGE) { if (eL) wb = 0; if (eR) wb = IMG_W - 12; }
    const bool topFix = (s0 == 0);                 // wave-uniform
    const bool botFix = (s0 + LSTRIP == IMG_H);    // wave-uniform

    v2f R[4][6];                 // raw ring (pairs), slot = k%4
    v2f hdR[3][3], hsR[3][3];    // separable partial rings
    float hfd[3], hfs[3];        // double-clamped edge-col partials
    v2f hxx[3][2], hyy[3][2], hxy[3][2];   // horizontal box-sum rings
    v4f o[LSTRIP];               // batched output rows

    auto issue = [&](int k) {
        int lr = s0 - 2 + k;                       // wave-uniform -> scalar
        lr = max(0, min(IMG_H - 1, lr));
        const float4* rp = (const float4*)(g + (size_t)lr * IMG_W + wb);
        const float4 A = rp[0], B = rp[1], C = rp[2];
        v2f* r = R[k % 4];
        r[0] = v2f{A.x, A.y}; r[1] = v2f{A.z, A.w};
        r[2] = v2f{B.x, B.y}; r[3] = v2f{B.z, B.w};
        r[4] = v2f{C.x, C.y}; r[5] = v2f{C.z, C.w};
    };

    issue(0); issue(1); issue(2);          // preload s0-2 .. s0

    const v2f two = {2.0f, 2.0f};

    #pragma unroll
    for (int k = 0; k < NK; ++k) {         // schedule row sr = s0-2+k
        if (k + 3 < NK) issue(k + 3);      // prefetch distance 3

        // ---- separable partials for schedule row k ----
        {
            const v2f* r = R[k % 4];
            v2f Za, Zb, Zc, Zd, Sab, Sbc, Scd;
            if (EDGE) {
                const float rs[12] = {r[0].x, r[0].y, r[1].x, r[1].y,
                                      r[2].x, r[2].y, r[3].x, r[3].y,
                                      r[4].x, r[4].y, r[5].x, r[5].y};
                const float zL[8] = {rs[0],rs[0],rs[0],rs[1],rs[2],rs[3],rs[4],rs[5]};
                const float zR[8] = {rs[6],rs[7],rs[8],rs[9],rs[10],rs[11],rs[11],rs[11]};
                float z[8];
                #pragma unroll
                for (int j = 0; j < 8; ++j)
                    z[j] = eL ? zL[j] : (eR ? zR[j] : rs[j + 2]);
                hfd[k % 3] = eR ? (z[5] - z[4]) : (z[3] - z[2]);
                hfs[k % 3] = eR ? (z[4] + 3.0f * z[5]) : (3.0f * z[2] + z[3]);
                Za = v2f{z[0], z[1]}; Zb = v2f{z[2], z[3]};
                Zc = v2f{z[4], z[5]}; Zd = v2f{z[6], z[7]};
                Sab = v2f{z[1], z[2]}; Sbc = v2f{z[3], z[4]}; Scd = v2f{z[5], z[6]};
            } else {
                Za = r[1]; Zb = r[2]; Zc = r[3]; Zd = r[4];
                Sab = v2f{r[1].y, r[2].x};
                Sbc = v2f{r[2].y, r[3].x};
                Scd = v2f{r[3].y, r[4].x};
            }
            v2f* hd = hdR[k % 3];
            v2f* hs = hsR[k % 3];
            hd[0] = Zb - Za; hd[1] = Zc - Zb; hd[2] = Zd - Zc;
            hs[0] = vfma2(Sab, two, Za) + Zb;
            hs[1] = vfma2(Sbc, two, Zb) + Zc;
            hs[2] = vfma2(Scd, two, Zc) + Zd;
        }

        // ---- product row vr = s0-1+(k-2) (k>=2) ----
        if (k >= 2) {
            const int rr = k - 2;
            const int sm = rr % 3, sz = (rr + 1) % 3, sp = (rr + 2) % 3;

            v2f Ixp[3], Iyp[3];
            #pragma unroll
            for (int j = 0; j < 3; ++j) {
                Ixp[j] = vfma2(hdR[sz][j], two, hdR[sm][j]) + hdR[sp][j];
                Iyp[j] = hsR[sp][j] - hsR[sm][j];
            }
            if (EDGE) {
                const float ixf = hfd[sm] + 2.0f * hfd[sz] + hfd[sp];
                const float iyf = hfs[sp] - hfs[sm];
                if (eL) { Ixp[0].x = ixf; Iyp[0].x = iyf; }
                if (eR) { Ixp[2].y = ixf; Iyp[2].y = iyf; }
            }

            v2f xx[3], yy[3], xy[3];
            #pragma unroll
            for (int j = 0; j < 3; ++j) {
                xx[j] = Ixp[j] * Ixp[j];
                yy[j] = Iyp[j] * Iyp[j];
                xy[j] = Ixp[j] * Iyp[j];
            }
            {
                v2f* hx = hxx[rr % 3];
                v2f* hy = hyy[rr % 3];
                v2f* hz = hxy[rr % 3];
                hx[0] = xx[0] + v2f{xx[0].y, xx[1].x} + xx[1];
                hx[1] = xx[1] + v2f{xx[1].y, xx[2].x} + xx[2];
                hy[0] = yy[0] + v2f{yy[0].y, yy[1].x} + yy[1];
                hy[1] = yy[1] + v2f{yy[1].y, yy[2].x} + yy[2];
                hz[0] = xy[0] + v2f{xy[0].y, xy[1].x} + xy[1];
                hz[1] = xy[1] + v2f{xy[1].y, xy[2].x} + xy[2];
            }
            // top: P(vr=-1) == P(vr=0)  (wave-uniform branch)
            if (rr == 1 && topFix) {
                #pragma unroll
                for (int q = 0; q < 2; ++q) {
                    hxx[0][q] = hxx[1][q]; hyy[0][q] = hyy[1][q]; hxy[0][q] = hxy[1][q];
                }
            }
            // bottom: P(vr=H) == P(vr=H-1)
            if (rr == LSTRIP + 1 && botFix) {
                #pragma unroll
                for (int q = 0; q < 2; ++q) {
                    hxx[rr % 3][q] = hxx[(rr - 1) % 3][q];
                    hyy[rr % 3][q] = hyy[(rr - 1) % 3][q];
                    hxy[rr % 3][q] = hxy[(rr - 1) % 3][q];
                }
            }

            if (rr >= 2) {
                const int a = (rr - 2) % 3, b2 = (rr - 1) % 3, c = rr % 3;
                float rv[4];
                #pragma unroll
                for (int q = 0; q < 2; ++q) {
                    const v2f sxx = hxx[a][q] + hxx[b2][q] + hxx[c][q];
                    const v2f syy = hyy[a][q] + hyy[b2][q] + hyy[c][q];
                    const v2f sxy = hxy[a][q] + hxy[b2][q] + hxy[c][q];
                    const v2f S = sxx + syy;
                    const v2f D = sxx - syy;
                    const v2f E = sxy + sxy;
                    const v2f disc = vfma2(D, D, vfma2(E, E, v2f{4e-10f, 4e-10f}));
                    const v2f qv = {__builtin_sqrtf(disc.x), __builtin_sqrtf(disc.y)};
                    const v2f lam = (S - qv) * 0.5f;
                    rv[2 * q]     = fmaxf(lam.x, 0.0f);
                    rv[2 * q + 1] = fmaxf(lam.y, 0.0f);
                }
                o[rr - 2] = v4f{rv[0], rv[1], rv[2], rv[3]};   // buffer, no store
            }
        }
    }

    // terminal store burst: loads are all retired; stores never gate loads
    float* orowp = outb + (size_t)s0 * IMG_W + vb;
    #pragma unroll
    for (int i = 0; i < LSTRIP; ++i) {
        __builtin_nontemporal_store(o[i], (v4f*)orowp);
        orowp += IMG_W;
    }
}

__global__ __launch_bounds__(256, 4)
void shi_tomasi_kernel(const float* __restrict__ img, float* __restrict__ out) {
    const int cg    = threadIdx.x & 63;            // 64 col-groups x 4 cols
    const int strip = threadIdx.x >> 6;            // wave-uniform strip 0..3
    const int vb = blockIdx.x * 256 + cg * 4;
    if (vb >= IMG_W) return;                       // masked half of block x=7
    const int s0 = blockIdx.y * BROWS + strip * LSTRIP;
    const float* g = img + (size_t)blockIdx.z * (IMG_H * IMG_W);
    float* outb = out + (size_t)blockIdx.z * (IMG_H * IMG_W);

    if (blockIdx.x == 0 || blockIdx.x == gridDim.x - 1)
        st_body<true>(g, outb, vb, s0);
    else
        st_body<false>(g, outb, vb, s0);
}

extern "C" void kernel_launch(void* const* d_in, const int* in_sizes, int n_in,
                              void* d_out, int out_size, void* d_ws, size_t ws_size,
                              hipStream_t stream) {
    const float* img = (const float*)d_in[0];
    float* out = (float*)d_out;
    dim3 grid(8, IMG_H / BROWS, NBATCH);           // 8 x 30 x 8 = 1920 blocks
    shi_tomasi_kernel<<<grid, 256, 0, stream>>>(img, out);
}

// Round 7
// 120.130 us; speedup vs baseline: 1.4101x; 1.4101x over previous
//
#include <hip/hip_runtime.h>

typedef float v2f __attribute__((ext_vector_type(2)));
typedef float v4f __attribute__((ext_vector_type(4)));

#define IMG_H 1080
#define IMG_W 1920
#define NBATCH 8
#define LSTRIP 9             // output rows per lane
#define BROWS (4*LSTRIP)     // 36 rows per block
#define NK (LSTRIP+4)        // 13 schedule iterations

// R7: single non-overlapping dwordx4 load per lane per row; ±2-col halo via
// ds_bpermute from neighbor lanes (R2-R5 issued 3 overlapping dwordx4/row ->
// 3x cache-line-request amplification; model says per-CU miss-throughput was
// the 43us plateau). Wave = 64 lanes x 4 cols = 256 loaded floats, 240 output
// cols; grid.x = 8 exact (1920 = 8*240). Lanes 60-63 load (clamped) but only
// feed shuffles; no early return anywhere (shuffle sources must execute).
// Block-edge left halo: 1-lane predicated 8B load/row. Image edges: validated
// replicate + hfd/hfs double-clamp algebra, branchless.

static __device__ __forceinline__ v2f vfma2(v2f a, v2f b, v2f c) {
    return __builtin_elementwise_fma(a, b, c);
}
static __device__ __forceinline__ float bperm(int addr, float v) {
    return __int_as_float(__builtin_amdgcn_ds_bpermute(addr, __float_as_int(v)));
}

__global__ __launch_bounds__(256, 4)
void shi_tomasi_kernel(const float* __restrict__ img, float* __restrict__ out) {
    const int cg    = threadIdx.x & 63;            // lane within wave
    const int strip = threadIdx.x >> 6;            // wave-uniform 0..3
    const int bx    = blockIdx.x;
    const int c0    = bx * 240 + cg * 4;           // first output col (lanes 0..59)
    const int c0l   = min(c0, IMG_W - 4);          // clamp (bx==7, lanes 60-63)
    const int s0    = blockIdx.y * BROWS + strip * LSTRIP;
    const float* g  = img + (size_t)blockIdx.z * (IMG_H * IMG_W);
    float* outb     = out + (size_t)blockIdx.z * (IMG_H * IMG_W);

    const bool eL     = (c0 == 0);                 // bx0 lane0
    const bool eR     = (c0 == IMG_W - 4);         // bx7 lane59
    const bool hload  = (cg == 0) && (bx > 0);     // needs left pair from prev block
    const bool doSt   = (cg < 60);
    const int  aLft   = 4 * (cg - 1);              // bpermute addrs
    const int  aRgt   = 4 * (cg + 1);
    const bool topFix = (s0 == 0);                 // wave-uniform
    const bool botFix = (s0 + LSTRIP == IMG_H);    // wave-uniform

    v4f Zr[4];                   // raw chunk ring
    v2f Hr[4] = {};              // left-halo pair ring (lane 0 of bx>0)
    v2f hdR[3][3], hsR[3][3];
    float hfd[3], hfs[3];
    v2f hxx[3][2], hyy[3][2], hxy[3][2];

    auto issue = [&](int k) {
        int lr = s0 - 2 + k;                       // wave-uniform -> scalar
        lr = max(0, min(IMG_H - 1, lr));
        const float* rowp = g + (size_t)lr * IMG_W;
        Zr[k % 4] = *(const v4f*)(rowp + c0l);
        if (hload) Hr[k % 4] = *(const v2f*)(rowp + (c0 - 2));
    };

    issue(0); issue(1); issue(2);

    const v2f two = {2.0f, 2.0f};

    #pragma unroll
    for (int k = 0; k < NK; ++k) {
        if (k + 3 < NK) issue(k + 3);

        // ---- separable partials for schedule row k ----
        {
            const v4f Z = Zr[k % 4];
            // halo via neighbor shuffles: z0,z1 = left lane's (z,w); z6,z7 = right's (x,y)
            const float zl0 = bperm(aLft, Z.z), zl1 = bperm(aLft, Z.w);
            const float zr0 = bperm(aRgt, Z.x), zr1 = bperm(aRgt, Z.y);
            v2f Z0 = v2f{zl0, zl1};
            if (cg == 0) Z0 = eL ? v2f{Z.x, Z.x} : Hr[k % 4];
            const v2f Z1 = v2f{Z.x, Z.y};
            const v2f Z2 = v2f{Z.z, Z.w};
            v2f Z3 = v2f{zr0, zr1};
            if (eR) Z3 = v2f{Z.w, Z.w};            // z6=z7=col W-1

            const v2f Sab = v2f{Z0.y, Z1.x};
            const v2f Sbc = v2f{Z1.y, Z2.x};
            const v2f Scd = v2f{Z2.y, Z3.x};
            v2f* hd = hdR[k % 3];
            v2f* hs = hsR[k % 3];
            hd[0] = Z1 - Z0; hd[1] = Z2 - Z1; hd[2] = Z3 - Z2;
            hs[0] = vfma2(Sab, two, Z0) + Z1;
            hs[1] = vfma2(Sbc, two, Z1) + Z2;
            hs[2] = vfma2(Scd, two, Z2) + Z3;
            // double-clamped edge-col partials (virtual col -1 / col W)
            hfd[k % 3] = eR ? (Z2.y - Z2.x) : (Z1.y - Z1.x);
            hfs[k % 3] = eR ? (Z2.x + 3.0f * Z2.y) : (3.0f * Z1.x + Z1.y);
        }

        // ---- product row vr = s0-1+(k-2) (k>=2) ----
        if (k >= 2) {
            const int rr = k - 2;
            const int sm = rr % 3, sz = (rr + 1) % 3, sp = (rr + 2) % 3;

            v2f Ixp[3], Iyp[3];
            #pragma unroll
            for (int j = 0; j < 3; ++j) {
                Ixp[j] = vfma2(hdR[sz][j], two, hdR[sm][j]) + hdR[sp][j];
                Iyp[j] = hsR[sp][j] - hsR[sm][j];
            }
            const float ixf = hfd[sm] + 2.0f * hfd[sz] + hfd[sp];
            const float iyf = hfs[sp] - hfs[sm];
            if (eL) { Ixp[0].x = ixf; Iyp[0].x = iyf; }
            if (eR) { Ixp[2].y = ixf; Iyp[2].y = iyf; }

            v2f xx[3], yy[3], xy[3];
            #pragma unroll
            for (int j = 0; j < 3; ++j) {
                xx[j] = Ixp[j] * Ixp[j];
                yy[j] = Iyp[j] * Iyp[j];
                xy[j] = Ixp[j] * Iyp[j];
            }
            {
                v2f* hx = hxx[rr % 3];
                v2f* hy = hyy[rr % 3];
                v2f* hz = hxy[rr % 3];
                hx[0] = xx[0] + v2f{xx[0].y, xx[1].x} + xx[1];
                hx[1] = xx[1] + v2f{xx[1].y, xx[2].x} + xx[2];
                hy[0] = yy[0] + v2f{yy[0].y, yy[1].x} + yy[1];
                hy[1] = yy[1] + v2f{yy[1].y, yy[2].x} + yy[2];
                hz[0] = xy[0] + v2f{xy[0].y, xy[1].x} + xy[1];
                hz[1] = xy[1] + v2f{xy[1].y, xy[2].x} + xy[2];
            }
            if (rr == 1 && topFix) {               // P(-1) == P(0)
                #pragma unroll
                for (int q = 0; q < 2; ++q) {
                    hxx[0][q] = hxx[1][q]; hyy[0][q] = hyy[1][q]; hxy[0][q] = hxy[1][q];
                }
            }
            if (rr == LSTRIP + 1 && botFix) {      // P(H) == P(H-1)
                #pragma unroll
                for (int q = 0; q < 2; ++q) {
                    hxx[rr % 3][q] = hxx[(rr - 1) % 3][q];
                    hyy[rr % 3][q] = hyy[(rr - 1) % 3][q];
                    hxy[rr % 3][q] = hxy[(rr - 1) % 3][q];
                }
            }

            if (rr >= 2) {
                const int a = (rr - 2) % 3, b2 = (rr - 1) % 3, c = rr % 3;
                float rv[4];
                #pragma unroll
                for (int q = 0; q < 2; ++q) {
                    const v2f sxx = hxx[a][q] + hxx[b2][q] + hxx[c][q];
                    const v2f syy = hyy[a][q] + hyy[b2][q] + hyy[c][q];
                    const v2f sxy = hxy[a][q] + hxy[b2][q] + hxy[c][q];
                    const v2f S = sxx + syy;
                    const v2f D = sxx - syy;
                    const v2f E = sxy + sxy;
                    const v2f disc = vfma2(D, D, vfma2(E, E, v2f{4e-10f, 4e-10f}));
                    const v2f qv = {__builtin_sqrtf(disc.x), __builtin_sqrtf(disc.y)};
                    const v2f lam = (S - qv) * 0.5f;
                    rv[2 * q]     = fmaxf(lam.x, 0.0f);
                    rv[2 * q + 1] = fmaxf(lam.y, 0.0f);
                }
                if (doSt) {
                    float* orowp = outb + (size_t)(s0 + rr - 2) * IMG_W + c0;
                    *(v4f*)orowp = v4f{rv[0], rv[1], rv[2], rv[3]};
                }
            }
        }
    }
}

extern "C" void kernel_launch(void* const* d_in, const int* in_sizes, int n_in,
                              void* d_out, int out_size, void* d_ws, size_t ws_size,
                              hipStream_t stream) {
    const float* img = (const float*)d_in[0];
    float* out = (float*)d_out;
    dim3 grid(8, IMG_H / BROWS, NBATCH);           // 8 x 30 x 8 = 1920 blocks
    shi_tomasi_kernel<<<grid, 256, 0, stream>>>(img, out);
}

// Round 8
// 117.999 us; speedup vs baseline: 1.4356x; 1.0181x over previous
//
#include <hip/hip_runtime.h>

typedef float v2f __attribute__((ext_vector_type(2)));
typedef float v4f __attribute__((ext_vector_type(4)));

#define IMG_H 1080
#define IMG_W 1920
#define NBATCH 8
#define LSTRIP 9             // output rows per lane
#define BROWS (4*LSTRIP)     // 36 rows per block
#define NK (LSTRIP+4)        // 13 schedule rows

// R8: "load-all-then-stream" — all 13 row loads issued before the compute
// loop (13 KB in flight/wave vs R7's 3 KB; theory: 41us plateau = load
// latency / prefetch-depth, not VALU or load count). Lane l loads chunk at
// base-8+4l so lanes 2..61 own their output's 4 cols exactly; halo = pure
// ds_bpermute, NO extra halo load (removes R7's Hr ring + predicated load).
// Edge algebra identical to validated R7 (replicate + hfd/hfs double-clamp,
// wave-uniform top/bot h-ring fixes). launch_bounds(256,3) for the ring.

static __device__ __forceinline__ v2f vfma2(v2f a, v2f b, v2f c) {
    return __builtin_elementwise_fma(a, b, c);
}
static __device__ __forceinline__ float bperm(int addr, float v) {
    return __int_as_float(__builtin_amdgcn_ds_bpermute(addr, __float_as_int(v)));
}

__global__ __launch_bounds__(256, 3)
void shi_tomasi_kernel(const float* __restrict__ img, float* __restrict__ out) {
    const int cg    = threadIdx.x & 63;            // lane within wave
    const int strip = threadIdx.x >> 6;            // wave-uniform 0..3
    const int bx    = blockIdx.x;
    const int base  = bx * 240;
    const int cl    = min(max(base - 8 + 4 * cg, 0), IMG_W - 4);  // load col
    const int c0    = base + 4 * (cg - 2);         // output col (lanes 2..61)
    const int s0    = blockIdx.y * BROWS + strip * LSTRIP;
    const float* g  = img + (size_t)blockIdx.z * (IMG_H * IMG_W);
    float* outb     = out + (size_t)blockIdx.z * (IMG_H * IMG_W);

    const bool eL     = (bx == 0) && (cg == 2);    // c0 == 0
    const bool eR     = (bx == 7) && (cg == 61);   // c0 == W-4
    const bool doSt   = (cg >= 2) && (cg < 62);
    const int  aLft   = 4 * (cg - 1);
    const int  aRgt   = 4 * (cg + 1);
    const bool topFix = (s0 == 0);                 // wave-uniform
    const bool botFix = (s0 + LSTRIP == IMG_H);    // wave-uniform

    v4f Zr[NK];                  // full raw window, all loads in flight
    const float* lp = g + cl;
    #pragma unroll
    for (int k = 0; k < NK; ++k) {
        int lr = s0 - 2 + k;                       // wave-uniform -> scalar
        lr = max(0, min(IMG_H - 1, lr));
        Zr[k] = *(const v4f*)(lp + (size_t)lr * IMG_W);
    }

    v2f hdR[3][3], hsR[3][3];
    float hfd[3], hfs[3];
    v2f hxx[3][2], hyy[3][2], hxy[3][2];
    const v2f two = {2.0f, 2.0f};

    #pragma unroll
    for (int k = 0; k < NK; ++k) {
        // ---- separable partials for schedule row k ----
        {
            const v4f Z = Zr[k];
            const float zl0 = bperm(aLft, Z.z), zl1 = bperm(aLft, Z.w);
            const float zr0 = bperm(aRgt, Z.x), zr1 = bperm(aRgt, Z.y);
            v2f Z0 = v2f{zl0, zl1};
            if (eL) Z0 = v2f{Z.x, Z.x};            // replicate col 0
            const v2f Z1 = v2f{Z.x, Z.y};
            const v2f Z2 = v2f{Z.z, Z.w};
            v2f Z3 = v2f{zr0, zr1};
            if (eR) Z3 = v2f{Z.w, Z.w};            // replicate col W-1

            const v2f Sab = v2f{Z0.y, Z1.x};
            const v2f Sbc = v2f{Z1.y, Z2.x};
            const v2f Scd = v2f{Z2.y, Z3.x};
            v2f* hd = hdR[k % 3];
            v2f* hs = hsR[k % 3];
            hd[0] = Z1 - Z0; hd[1] = Z2 - Z1; hd[2] = Z3 - Z2;
            hs[0] = vfma2(Sab, two, Z0) + Z1;
            hs[1] = vfma2(Sbc, two, Z1) + Z2;
            hs[2] = vfma2(Scd, two, Z2) + Z3;
            // double-clamped edge-col partials (virtual col -1 / col W)
            hfd[k % 3] = eR ? (Z2.y - Z2.x) : (Z1.y - Z1.x);
            hfs[k % 3] = eR ? (Z2.x + 3.0f * Z2.y) : (3.0f * Z1.x + Z1.y);
        }

        // ---- product row vr = s0-1+(k-2) (k>=2) ----
        if (k >= 2) {
            const int rr = k - 2;
            const int sm = rr % 3, sz = (rr + 1) % 3, sp = (rr + 2) % 3;

            v2f Ixp[3], Iyp[3];
            #pragma unroll
            for (int j = 0; j < 3; ++j) {
                Ixp[j] = vfma2(hdR[sz][j], two, hdR[sm][j]) + hdR[sp][j];
                Iyp[j] = hsR[sp][j] - hsR[sm][j];
            }
            const float ixf = hfd[sm] + 2.0f * hfd[sz] + hfd[sp];
            const float iyf = hfs[sp] - hfs[sm];
            if (eL) { Ixp[0].x = ixf; Iyp[0].x = iyf; }
            if (eR) { Ixp[2].y = ixf; Iyp[2].y = iyf; }

            v2f xx[3], yy[3], xy[3];
            #pragma unroll
            for (int j = 0; j < 3; ++j) {
                xx[j] = Ixp[j] * Ixp[j];
                yy[j] = Iyp[j] * Iyp[j];
                xy[j] = Ixp[j] * Iyp[j];
            }
            {
                v2f* hx = hxx[rr % 3];
                v2f* hy = hyy[rr % 3];
                v2f* hz = hxy[rr % 3];
                hx[0] = xx[0] + v2f{xx[0].y, xx[1].x} + xx[1];
                hx[1] = xx[1] + v2f{xx[1].y, xx[2].x} + xx[2];
                hy[0] = yy[0] + v2f{yy[0].y, yy[1].x} + yy[1];
                hy[1] = yy[1] + v2f{yy[1].y, yy[2].x} + yy[2];
                hz[0] = xy[0] + v2f{xy[0].y, xy[1].x} + xy[1];
                hz[1] = xy[1] + v2f{xy[1].y, xy[2].x} + xy[2];
            }
            if (rr == 1 && topFix) {               // P(-1) == P(0)
                #pragma unroll
                for (int q = 0; q < 2; ++q) {
                    hxx[0][q] = hxx[1][q]; hyy[0][q] = hyy[1][q]; hxy[0][q] = hxy[1][q];
                }
            }
            if (rr == LSTRIP + 1 && botFix) {      // P(H) == P(H-1)
                #pragma unroll
                for (int q = 0; q < 2; ++q) {
                    hxx[rr % 3][q] = hxx[(rr - 1) % 3][q];
                    hyy[rr % 3][q] = hyy[(rr - 1) % 3][q];
                    hxy[rr % 3][q] = hxy[(rr - 1) % 3][q];
                }
            }

            if (rr >= 2) {
                const int a = (rr - 2) % 3, b2 = (rr - 1) % 3, c = rr % 3;
                float rv[4];
                #pragma unroll
                for (int q = 0; q < 2; ++q) {
                    const v2f sxx = hxx[a][q] + hxx[b2][q] + hxx[c][q];
                    const v2f syy = hyy[a][q] + hyy[b2][q] + hyy[c][q];
                    const v2f sxy = hxy[a][q] + hxy[b2][q] + hxy[c][q];
                    const v2f S = sxx + syy;
                    const v2f D = sxx - syy;
                    const v2f E = sxy + sxy;
                    const v2f disc = vfma2(D, D, vfma2(E, E, v2f{4e-10f, 4e-10f}));
                    const v2f qv = {__builtin_sqrtf(disc.x), __builtin_sqrtf(disc.y)};
                    const v2f lam = (S - qv) * 0.5f;
                    rv[2 * q]     = fmaxf(lam.x, 0.0f);
                    rv[2 * q + 1] = fmaxf(lam.y, 0.0f);
                }
                if (doSt) {
                    float* orowp = outb + (size_t)(s0 + rr - 2) * IMG_W + c0;
                    *(v4f*)orowp = v4f{rv[0], rv[1], rv[2], rv[3]};
                }
            }
        }
    }
}

extern "C" void kernel_launch(void* const* d_in, const int* in_sizes, int n_in,
                              void* d_out, int out_size, void* d_ws, size_t ws_size,
                              hipStream_t stream) {
    const float* img = (const float*)d_in[0];
    float* out = (float*)d_out;
    dim3 grid(8, IMG_H / BROWS, NBATCH);           // 8 x 30 x 8 = 1920 blocks
    shi_tomasi_kernel<<<grid, 256, 0, stream>>>(img, out);
}